// Round 1
// baseline (111.317 us; speedup 1.0000x reference)
//
#include <hip/hip_runtime.h>

// Problem constants (from reference)
constexpr int Bc  = 4;
constexpr int Cc  = 64;
constexpr int H0  = 128;
constexpr int W0  = 128;
constexpr int Gc  = 4;
constexpr int CG  = Cc / Gc;     // 16 channels per group
constexpr int HOc = H0 * 2;      // 256
constexpr int WOc = W0 * 2;      // 256

// ---------------------------------------------------------------------------
// K1: offset conv (gated) + bilinear border sampling -> x_def (in d_ws)
// One block = 16x16 output tile for one (b, g). Thread = one output pixel.
// ---------------------------------------------------------------------------
__global__ __launch_bounds__(256) void k1_sample(
    const float* __restrict__ x,
    const float* __restrict__ w_off,  const float* __restrict__ b_off,
    const float* __restrict__ w_offm, const float* __restrict__ b_offm,
    float* __restrict__ xdef)
{
    // 8 offset rows for this group (sy*4+sx*2+d), padded to 65 to avoid bank conflicts
    __shared__ float wof[8][65];
    __shared__ float wom[8][65];

    const int bg = blockIdx.y;           // b*G + g
    const int b  = bg >> 2;
    const int g  = bg & 3;
    const int tile = blockIdx.x;         // 256 tiles of 16x16 over 256x256
    const int oy = (tile >> 4) * 16;
    const int ox = (tile & 15) * 16;
    const int t  = threadIdx.x;

    for (int i = t; i < 8 * 64; i += 256) {
        const int r = i >> 6, c = i & 63;
        wof[r][c] = w_off [(g * 8 + r) * Cc + c];
        wom[r][c] = w_offm[(g * 8 + r) * Cc + c];
    }
    __syncthreads();

    const int tx = t & 15, ty = t >> 4;
    const int wo = ox + tx, ho = oy + ty;
    const int sx = wo & 1,  sy = ho & 1;
    const int h  = ho >> 1, w  = wo >> 1;
    const int r0 = sy * 4 + sx * 2;      // d=0 row; r0+1 is d=1

    float a0 = 0.f, a1 = 0.f, m0 = 0.f, m1 = 0.f;
    const float* xb = x + (size_t)b * Cc * H0 * W0 + h * W0 + w;
#pragma unroll 8
    for (int c = 0; c < Cc; ++c) {
        const float xv = xb[c * H0 * W0];
        a0 = fmaf(wof[r0    ][c], xv, a0);
        a1 = fmaf(wof[r0 + 1][c], xv, a1);
        m0 = fmaf(wom[r0    ][c], xv, m0);
        m1 = fmaf(wom[r0 + 1][c], xv, m1);
    }
    a0 += b_off [g * 8 + r0];
    a1 += b_off [g * 8 + r0 + 1];
    m0 += b_offm[g * 8 + r0];
    m1 += b_offm[g * 8 + r0 + 1];

    const float offx = a0 / (1.f + __expf(-m0));   // off * sigmoid(offm)
    const float offy = a1 / (1.f + __expf(-m1));

    // source coords (grid_sample bilinear, padding 'border')
    float ix = (wo + 0.5f + offx) * 0.5f - 0.5f;
    float iy = (ho + 0.5f + offy) * 0.5f - 0.5f;
    ix = fminf(fmaxf(ix, 0.f), (float)(W0 - 1));
    iy = fminf(fmaxf(iy, 0.f), (float)(H0 - 1));
    const float x0f = floorf(ix), y0f = floorf(iy);
    const float wx = ix - x0f,   wy = iy - y0f;
    const int x0 = (int)x0f, y0 = (int)y0f;
    const int x1 = min(x0 + 1, W0 - 1), y1 = min(y0 + 1, H0 - 1);
    const float w00 = (1.f - wx) * (1.f - wy);
    const float w01 = wx * (1.f - wy);
    const float w10 = (1.f - wx) * wy;
    const float w11 = wx * wy;

    const int o00 = y0 * W0 + x0, o01 = y0 * W0 + x1;
    const int o10 = y1 * W0 + x0, o11 = y1 * W0 + x1;

    const float* xg = x    + ((size_t)b * Cc + g * CG) * H0 * W0;
    float*       xd = xdef + ((size_t)b * Cc + g * CG) * HOc * WOc + ho * WOc + wo;
#pragma unroll 4
    for (int c = 0; c < CG; ++c) {
        const float* pc = xg + (size_t)c * H0 * W0;
        const float v = w00 * pc[o00] + w01 * pc[o01] + w10 * pc[o10] + w11 * pc[o11];
        xd[(size_t)c * HOc * WOc] = v;
    }
}

// ---------------------------------------------------------------------------
// K2: gated kernel conv (9ch) + softmax + 3x3 dynamic conv -> out
// One block = 16x16 output tile for one b. Thread = one output pixel.
// Weights read with wave-uniform indices (scalar-load path), no LDS needed.
// ---------------------------------------------------------------------------
__global__ __launch_bounds__(256) void k2_dynconv(
    const float* __restrict__ xdef,
    const float* __restrict__ w_sk, const float* __restrict__ b_sk,
    const float* __restrict__ w_km, const float* __restrict__ b_km,
    float* __restrict__ out)
{
    const int b    = blockIdx.y;
    const int tile = blockIdx.x;
    const int oy = (tile >> 4) * 16;
    const int ox = (tile & 15) * 16;
    const int t  = threadIdx.x;
    const int tx = t & 15, ty = t >> 4;
    const int wo = ox + tx, ho = oy + ty;

    const float* xb = xdef + (size_t)b * Cc * HOc * WOc;

    float ask[9], akm[9];
#pragma unroll
    for (int k = 0; k < 9; ++k) { ask[k] = 0.f; akm[k] = 0.f; }

    const float* pc0 = xb + ho * WOc + wo;
    for (int c = 0; c < Cc; ++c) {
        const float xv = pc0[(size_t)c * HOc * WOc];
#pragma unroll
        for (int k = 0; k < 9; ++k) {
            ask[k] = fmaf(w_sk[k * Cc + c], xv, ask[k]);   // uniform -> s_load
            akm[k] = fmaf(w_km[k * Cc + c], xv, akm[k]);
        }
    }

    float sv[9], mx = -1e30f;
#pragma unroll
    for (int k = 0; k < 9; ++k) {
        const float z = akm[k] + b_km[k];
        sv[k] = (ask[k] + b_sk[k]) / (1.f + __expf(-z));
        mx = fmaxf(mx, sv[k]);
    }
    float sum = 0.f;
#pragma unroll
    for (int k = 0; k < 9; ++k) { sv[k] = __expf(sv[k] - mx); sum += sv[k]; }
    const float inv = 1.f / sum;
#pragma unroll
    for (int k = 0; k < 9; ++k) sv[k] *= inv;

    // 3x3 dynamic conv with zero padding
    for (int c = 0; c < Cc; ++c) {
        const float* p = xb + (size_t)c * HOc * WOc;
        float acc = 0.f;
#pragma unroll
        for (int ky = 0; ky < 3; ++ky) {
            const int y = ho + ky - 1;
#pragma unroll
            for (int kx = 0; kx < 3; ++kx) {
                const int xx = wo + kx - 1;
                const bool inb = (y >= 0) & (y < HOc) & (xx >= 0) & (xx < WOc);
                const float v = inb ? p[y * WOc + xx] : 0.f;
                acc = fmaf(sv[ky * 3 + kx], v, acc);
            }
        }
        out[((size_t)b * Cc + c) * HOc * WOc + ho * WOc + wo] = acc;
    }
}

// ---------------------------------------------------------------------------
extern "C" void kernel_launch(void* const* d_in, const int* in_sizes, int n_in,
                              void* d_out, int out_size, void* d_ws, size_t ws_size,
                              hipStream_t stream)
{
    const float* x      = (const float*)d_in[0];
    const float* w_off  = (const float*)d_in[1];
    const float* b_off  = (const float*)d_in[2];
    const float* w_offm = (const float*)d_in[3];
    const float* b_offm = (const float*)d_in[4];
    const float* w_sk   = (const float*)d_in[5];
    const float* b_sk   = (const float*)d_in[6];
    const float* w_km   = (const float*)d_in[7];
    const float* b_km   = (const float*)d_in[8];
    float* outp = (float*)d_out;

    const size_t xdef_bytes = (size_t)Bc * Cc * HOc * WOc * sizeof(float); // 64 MiB
    if (ws_size < xdef_bytes) return;  // refuse to corrupt memory; will fail loudly
    float* xdef = (float*)d_ws;

    dim3 blk(256);
    dim3 g1(256, Bc * Gc);   // 16x16 tiles x (b,g)
    hipLaunchKernelGGL(k1_sample, g1, blk, 0, stream,
                       x, w_off, b_off, w_offm, b_offm, xdef);

    dim3 g2(256, Bc);        // 16x16 tiles x b
    hipLaunchKernelGGL(k2_dynconv, g2, blk, 0, stream,
                       xdef, w_sk, b_sk, w_km, b_km, outp);
}

// Round 2
// 88.971 us; speedup vs baseline: 1.2512x; 1.2512x over previous
//
#include <hip/hip_runtime.h>

constexpr int Bc  = 4;
constexpr int Cc  = 64;
constexpr int H0  = 128;
constexpr int W0  = 128;
constexpr int Gc  = 4;
constexpr int CG  = Cc / Gc;     // 16
constexpr int HOc = H0 * 2;      // 256
constexpr int WOc = W0 * 2;      // 256

constexpr int TW = 16;           // output tile width
constexpr int TH = 8;            // output tile height
constexpr int HX = TW + 2;       // 18 halo cols
constexpr int HY = TH + 2;       // 10 halo rows
constexpr int NHALO = HX * HY;   // 180
constexpr int NTASK = Gc * NHALO;// 720

// ---------------------------------------------------------------------------
// k0: gated offset conv for ALL (b,g,pixel) -> offbuf[bg][r][h][w], r=sy*4+sx*2+d
// Thread = one (b,g,h,w); weights via wave-uniform indices (scalar loads).
// ---------------------------------------------------------------------------
__global__ __launch_bounds__(256) void k0_offsets(
    const float* __restrict__ x,
    const float* __restrict__ w_off,  const float* __restrict__ b_off,
    const float* __restrict__ w_offm, const float* __restrict__ b_offm,
    float* __restrict__ offbuf)
{
    const int bg = blockIdx.y;            // b*4+g
    const int b  = bg >> 2, g = bg & 3;
    const int t  = threadIdx.x;
    const int tile = blockIdx.x;          // 8x8 tiles of 16x16 pixels
    const int h = (tile >> 3) * 16 + (t >> 4);
    const int w = (tile & 7)  * 16 + (t & 15);

    const float* xp = x + (size_t)b * Cc * H0 * W0 + h * W0 + w;
    const float* Wa = w_off  + (g * 8) * Cc;
    const float* Wm = w_offm + (g * 8) * Cc;

    float a[8], m[8];
#pragma unroll
    for (int r = 0; r < 8; ++r) { a[r] = 0.f; m[r] = 0.f; }

    for (int c = 0; c < Cc; ++c) {
        const float xv = xp[c * H0 * W0];
#pragma unroll
        for (int r = 0; r < 8; ++r) {
            a[r] = fmaf(Wa[r * Cc + c], xv, a[r]);   // uniform index -> s_load
            m[r] = fmaf(Wm[r * Cc + c], xv, m[r]);
        }
    }

    float* ob = offbuf + ((size_t)bg * 8) * (H0 * W0) + h * W0 + w;
#pragma unroll
    for (int r = 0; r < 8; ++r) {
        const float av = a[r] + b_off [g * 8 + r];
        const float mv = m[r] + b_offm[g * 8 + r];
        ob[r * H0 * W0] = av / (1.f + __expf(-mv));  // off * sigmoid(offm)
    }
}

// ---------------------------------------------------------------------------
// k1_fused: bilinear halo -> LDS, sk/km+softmax, 3x3 dynamic conv -> out.
// Block = 16x8 output tile for one b. 256 threads. LDS 55.3 KB -> 2 blocks/CU.
// ---------------------------------------------------------------------------
__global__ __launch_bounds__(256) void k1_fused(
    const float* __restrict__ x, const float* __restrict__ offbuf,
    const float* __restrict__ w_sk, const float* __restrict__ b_sk,
    const float* __restrict__ w_km, const float* __restrict__ b_km,
    float* __restrict__ out)
{
    __shared__ float xd[Cc][NHALO];        // 64 x 180 floats = 46.1 KB
    __shared__ float kmb [TW * TH][9];     // 4.6 KB
    __shared__ float sknb[TW * TH][9];     // 4.6 KB

    const int b    = blockIdx.y;
    const int tile = blockIdx.x;           // 16 x-tiles * 32 y-tiles = 512
    const int ox = (tile & 15) * TW;
    const int oy = (tile >> 4) * TH;
    const int t  = threadIdx.x;

    // ---- phase 1: build x_def halo in LDS ----
    for (int task = t; task < NTASK; task += 256) {
        const int g   = task / NHALO;
        const int pix = task - g * NHALO;
        const int hy  = pix / HX;
        const int hx  = pix - hy * HX;
        const int gy  = oy - 1 + hy;
        const int gx  = ox - 1 + hx;
        if (gy < 0 || gy >= HOc || gx < 0 || gx >= WOc) {
#pragma unroll
            for (int c = 0; c < CG; ++c) xd[g * CG + c][pix] = 0.f;  // zero pad
            continue;
        }
        const int sy = gy & 1, sx = gx & 1;
        const int h  = gy >> 1, w  = gx >> 1;
        const int r0 = sy * 4 + sx * 2;
        const int bg = b * 4 + g;
        const size_t obase = ((size_t)bg * 8 + r0) * (H0 * W0) + h * W0 + w;
        const float offx = offbuf[obase];
        const float offy = offbuf[obase + H0 * W0];

        float ix = ((float)gx + 0.5f + offx) * 0.5f - 0.5f;
        float iy = ((float)gy + 0.5f + offy) * 0.5f - 0.5f;
        ix = fminf(fmaxf(ix, 0.f), (float)(W0 - 1));
        iy = fminf(fmaxf(iy, 0.f), (float)(H0 - 1));
        const float x0f = floorf(ix), y0f = floorf(iy);
        const float wx = ix - x0f,   wy = iy - y0f;
        const int x0 = (int)x0f, y0 = (int)y0f;
        const int x1 = min(x0 + 1, W0 - 1), y1 = min(y0 + 1, H0 - 1);
        const float w00 = (1.f - wx) * (1.f - wy);
        const float w01 = wx * (1.f - wy);
        const float w10 = (1.f - wx) * wy;
        const float w11 = wx * wy;
        const int o00 = y0 * W0 + x0, o01 = y0 * W0 + x1;
        const int o10 = y1 * W0 + x0, o11 = y1 * W0 + x1;

        const float* xg = x + ((size_t)b * Cc + g * CG) * (H0 * W0);
#pragma unroll 4
        for (int c = 0; c < CG; ++c) {
            const float* pc = xg + (size_t)c * (H0 * W0);
            xd[g * CG + c][pix] =
                w00 * pc[o00] + w01 * pc[o01] + w10 * pc[o10] + w11 * pc[o11];
        }
    }
    __syncthreads();

    // ---- phase 2: sk/km dots (split across halves), gate + softmax ----
    {
        const int p   = t & 127;
        const int ctr = ((p >> 4) + 1) * HX + (p & 15) + 1;
        float acc[9];
#pragma unroll
        for (int k = 0; k < 9; ++k) acc[k] = 0.f;

        if (t < 128) {
            for (int c = 0; c < Cc; ++c) {
                const float xv = xd[c][ctr];
#pragma unroll
                for (int k = 0; k < 9; ++k)
                    acc[k] = fmaf(w_sk[k * Cc + c], xv, acc[k]);
            }
        } else {
            for (int c = 0; c < Cc; ++c) {
                const float xv = xd[c][ctr];
#pragma unroll
                for (int k = 0; k < 9; ++k)
                    acc[k] = fmaf(w_km[k * Cc + c], xv, acc[k]);
            }
#pragma unroll
            for (int k = 0; k < 9; ++k) kmb[p][k] = acc[k];
        }
        __syncthreads();

        if (t < 128) {
            float sv[9], mx = -1e30f;
#pragma unroll
            for (int k = 0; k < 9; ++k) {
                const float z = kmb[p][k] + b_km[k];
                sv[k] = (acc[k] + b_sk[k]) / (1.f + __expf(-z));
                mx = fmaxf(mx, sv[k]);
            }
            float sum = 0.f;
#pragma unroll
            for (int k = 0; k < 9; ++k) { sv[k] = __expf(sv[k] - mx); sum += sv[k]; }
            const float inv = 1.f / sum;
#pragma unroll
            for (int k = 0; k < 9; ++k) sknb[p][k] = sv[k] * inv;
        }
    }
    __syncthreads();

    // ---- phase 3: 3x3 dynamic conv, 2x2 pixel register blocking ----
    {
        const int sq    = t & 31;         // 8x4 squares of 2x2 pixels
        const int chunk = t >> 5;         // 8 channel chunks
        const int sqx = sq & 7, sqy = sq >> 3;
        const int hx0 = 2 * sqx, hy0 = 2 * sqy;
        const int p00 = (2 * sqy) * TW + 2 * sqx;

        float s00[9], s01[9], s10[9], s11[9];
#pragma unroll
        for (int k = 0; k < 9; ++k) {
            s00[k] = sknb[p00][k];          s01[k] = sknb[p00 + 1][k];
            s10[k] = sknb[p00 + TW][k];     s11[k] = sknb[p00 + TW + 1][k];
        }
        const int orow0 = oy + 2 * sqy, ocol0 = ox + 2 * sqx;

#pragma unroll 2
        for (int i = 0; i < 8; ++i) {
            const int c = chunk * 8 + i;
            float wd[4][4];
#pragma unroll
            for (int ry = 0; ry < 4; ++ry) {
                const float2 u0 = *reinterpret_cast<const float2*>(&xd[c][(hy0 + ry) * HX + hx0]);
                const float2 u1 = *reinterpret_cast<const float2*>(&xd[c][(hy0 + ry) * HX + hx0 + 2]);
                wd[ry][0] = u0.x; wd[ry][1] = u0.y; wd[ry][2] = u1.x; wd[ry][3] = u1.y;
            }
            float a00 = 0.f, a01 = 0.f, a10 = 0.f, a11 = 0.f;
#pragma unroll
            for (int ky = 0; ky < 3; ++ky)
#pragma unroll
                for (int kx = 0; kx < 3; ++kx) {
                    const int k = ky * 3 + kx;
                    a00 = fmaf(s00[k], wd[ky    ][kx    ], a00);
                    a01 = fmaf(s01[k], wd[ky    ][kx + 1], a01);
                    a10 = fmaf(s10[k], wd[ky + 1][kx    ], a10);
                    a11 = fmaf(s11[k], wd[ky + 1][kx + 1], a11);
                }
            float* ob = out + ((size_t)(b * Cc + c)) * (HOc * WOc)
                            + (size_t)orow0 * WOc + ocol0;
            *reinterpret_cast<float2*>(ob)       = make_float2(a00, a01);
            *reinterpret_cast<float2*>(ob + WOc) = make_float2(a10, a11);
        }
    }
}

// ---------------------------------------------------------------------------
extern "C" void kernel_launch(void* const* d_in, const int* in_sizes, int n_in,
                              void* d_out, int out_size, void* d_ws, size_t ws_size,
                              hipStream_t stream)
{
    const float* x      = (const float*)d_in[0];
    const float* w_off  = (const float*)d_in[1];
    const float* b_off  = (const float*)d_in[2];
    const float* w_offm = (const float*)d_in[3];
    const float* b_offm = (const float*)d_in[4];
    const float* w_sk   = (const float*)d_in[5];
    const float* b_sk   = (const float*)d_in[6];
    const float* w_km   = (const float*)d_in[7];
    const float* b_km   = (const float*)d_in[8];
    float* outp = (float*)d_out;

    const size_t off_bytes = (size_t)Bc * Gc * 8 * H0 * W0 * sizeof(float); // 8 MiB
    if (ws_size < off_bytes) return;
    float* offbuf = (float*)d_ws;

    dim3 blk(256);
    dim3 g0(64, Bc * Gc);            // 16x16-pixel tiles x (b,g)
    hipLaunchKernelGGL(k0_offsets, g0, blk, 0, stream,
                       x, w_off, b_off, w_offm, b_offm, offbuf);

    dim3 g1(512, Bc);                // 16x8 output tiles x b
    hipLaunchKernelGGL(k1_fused, g1, blk, 0, stream,
                       x, offbuf, w_sk, b_sk, w_km, b_km, outp);
}

// Round 3
// 68.307 us; speedup vs baseline: 1.6296x; 1.3025x over previous
//
#include <hip/hip_runtime.h>
#include <hip/hip_fp16.h>

constexpr int Bc  = 4;
constexpr int Cc  = 64;
constexpr int H0  = 128;
constexpr int W0  = 128;
constexpr int HW  = H0 * W0;
constexpr int Gc  = 4;
constexpr int CG  = Cc / Gc;     // 16
constexpr int HOc = H0 * 2;      // 256
constexpr int WOc = W0 * 2;      // 256

constexpr int TW = 16;           // output tile width
constexpr int TH = 8;            // output tile height
constexpr int HX = TW + 2;       // 18 halo cols
constexpr int HY = TH + 2;       // 10 halo rows
constexpr int NHALO = HX * HY;   // 180
constexpr int NTASK = Gc * NHALO;// 720

constexpr int SXC = 10;          // staged input cols  (ox/2-1 .. ox/2+8)
constexpr int SYC = 6;           // staged input rows  (oy/2-1 .. oy/2+4)
constexpr int SN  = SXC * SYC;   // 60 floats per channel

// ---------------------------------------------------------------------------
// k0: gated offset conv. Thread = 2 adjacent pixels (float2 x loads),
// 32 accumulators, weights via wave-uniform scalar loads.
// offbuf[bg][r][h][w], r = sy*4 + sx*2 + d, values already gated.
// ---------------------------------------------------------------------------
__global__ __launch_bounds__(256) void k0_offsets(
    const float* __restrict__ x,
    const float* __restrict__ w_off,  const float* __restrict__ b_off,
    const float* __restrict__ w_offm, const float* __restrict__ b_offm,
    float* __restrict__ offbuf)
{
    const int bg = blockIdx.y;            // b*4+g
    const int b  = bg >> 2, g = bg & 3;
    const int pp = blockIdx.x * 256 + threadIdx.x;   // pixel-pair id
    const int h  = pp >> 6;
    const int w  = (pp & 63) << 1;

    const float2* xp = reinterpret_cast<const float2*>(
        x + (size_t)b * Cc * HW + h * W0 + w);
    const float* Wa = w_off  + (g * 8) * Cc;
    const float* Wm = w_offm + (g * 8) * Cc;

    float a0[8], a1[8], m0[8], m1[8];
#pragma unroll
    for (int r = 0; r < 8; ++r) { a0[r] = a1[r] = m0[r] = m1[r] = 0.f; }

#pragma unroll 4
    for (int c = 0; c < Cc; ++c) {
        const float2 xv = xp[c * (HW >> 1)];
#pragma unroll
        for (int r = 0; r < 8; ++r) {
            const float wa = Wa[r * Cc + c];   // uniform -> s_load
            const float wm = Wm[r * Cc + c];
            a0[r] = fmaf(wa, xv.x, a0[r]);
            a1[r] = fmaf(wa, xv.y, a1[r]);
            m0[r] = fmaf(wm, xv.x, m0[r]);
            m1[r] = fmaf(wm, xv.y, m1[r]);
        }
    }

    float* ob = offbuf + ((size_t)bg * 8) * HW + h * W0 + w;
#pragma unroll
    for (int r = 0; r < 8; ++r) {
        const float ba = b_off [g * 8 + r];
        const float bm = b_offm[g * 8 + r];
        const float o0 = (a0[r] + ba) / (1.f + __expf(-(m0[r] + bm)));
        const float o1 = (a1[r] + ba) / (1.f + __expf(-(m1[r] + bm)));
        *reinterpret_cast<float2*>(&ob[(size_t)r * HW]) = make_float2(o0, o1);
    }
}

// ---------------------------------------------------------------------------
// k1_fused: stage x window -> LDS, bilinear -> fp16 xd halo, sk/km+softmax,
// 3x3 dynamic conv. Block = 16x8 output tile. LDS 37.5 KB -> 4 blocks/CU.
// ---------------------------------------------------------------------------
__global__ __launch_bounds__(256) void k1_fused(
    const float* __restrict__ x, const float* __restrict__ offbuf,
    const float* __restrict__ w_sk, const float* __restrict__ b_sk,
    const float* __restrict__ w_km, const float* __restrict__ b_km,
    float* __restrict__ out)
{
    __shared__ __half xd[Cc][NHALO];      // 23040 B
    __shared__ float  ovl[Cc * SN];       // 15360 B: xstage, later kmb|sknb
    float* xstage = ovl;                  // [c][6][10]
    float* kmb    = ovl;                  // [128][9]
    float* sknb   = ovl + 128 * 9;        // [128][9]

    const int b    = blockIdx.y;
    const int tile = blockIdx.x;          // 16 x-tiles * 32 y-tiles
    const int ox = (tile & 15) * TW;
    const int oy = (tile >> 4) * TH;
    const int t  = threadIdx.x;
    const int syr = (oy >> 1) - 1;        // staged window origin (input coords)
    const int sxr = (ox >> 1) - 1;

    const float* xb = x + (size_t)b * Cc * HW;

    // ---- phase A: stage 6x10 input window, all 64 channels (border-clamped)
    for (int i = t; i < Cc * SN; i += 256) {
        const int c   = i / SN;
        const int rem = i - c * SN;
        const int r   = rem / SXC;
        const int j   = rem - r * SXC;
        const int yy  = min(max(syr + r, 0), H0 - 1);
        const int xx  = min(max(sxr + j, 0), W0 - 1);
        xstage[i] = xb[(size_t)c * HW + yy * W0 + xx];
    }
    __syncthreads();

    // ---- phase B: bilinear sample halo -> xd (fp16) ----
    for (int task = t; task < NTASK; task += 256) {
        const int g   = task / NHALO;
        const int pix = task - g * NHALO;
        const int hy  = pix / HX;
        const int hx  = pix - hy * HX;
        const int gy  = oy - 1 + hy;
        const int gx  = ox - 1 + hx;
        if (gy < 0 || gy >= HOc || gx < 0 || gx >= WOc) {
#pragma unroll 4
            for (int c = 0; c < CG; ++c) xd[g * CG + c][pix] = __half(0.f);
            continue;
        }
        const int sy = gy & 1, sx = gx & 1;
        const int h  = gy >> 1, w  = gx >> 1;
        const int r0 = sy * 4 + sx * 2;
        const int bg = b * 4 + g;
        const size_t obase = ((size_t)bg * 8 + r0) * HW + h * W0 + w;
        const float offx = offbuf[obase];
        const float offy = offbuf[obase + HW];

        float ix = ((float)gx + 0.5f + offx) * 0.5f - 0.5f;
        float iy = ((float)gy + 0.5f + offy) * 0.5f - 0.5f;
        ix = fminf(fmaxf(ix, 0.f), (float)(W0 - 1));
        iy = fminf(fmaxf(iy, 0.f), (float)(H0 - 1));
        const float x0f = floorf(ix), y0f = floorf(iy);
        const float wx = ix - x0f,   wy = iy - y0f;
        const int x0 = (int)x0f, y0 = (int)y0f;
        const int x1 = min(x0 + 1, W0 - 1), y1 = min(y0 + 1, H0 - 1);
        const float w00 = (1.f - wx) * (1.f - wy);
        const float w01 = wx * (1.f - wy);
        const float w10 = (1.f - wx) * wy;
        const float w11 = wx * wy;

        const int j0 = x0 - sxr, j1 = x1 - sxr;
        const int i0 = y0 - syr, i1 = y1 - syr;
        const bool inl = (j0 >= 0) & (j1 < SXC) & (i0 >= 0) & (i1 < SYC);

        if (inl) {
            const int o00 = i0 * SXC + j0, o01 = i0 * SXC + j1;
            const int o10 = i1 * SXC + j0, o11 = i1 * SXC + j1;
            const float* s = xstage + (g * CG) * SN;
#pragma unroll 4
            for (int c = 0; c < CG; ++c) {
                const float* pc = s + c * SN;
                const float v = w00 * pc[o00] + w01 * pc[o01]
                              + w10 * pc[o10] + w11 * pc[o11];
                xd[g * CG + c][pix] = __float2half(v);
            }
        } else {  // rare: tap escaped staged window -> global
            const int o00 = y0 * W0 + x0, o01 = y0 * W0 + x1;
            const int o10 = y1 * W0 + x0, o11 = y1 * W0 + x1;
            const float* xg = xb + (size_t)(g * CG) * HW;
#pragma unroll 4
            for (int c = 0; c < CG; ++c) {
                const float* pc = xg + (size_t)c * HW;
                const float v = w00 * pc[o00] + w01 * pc[o01]
                              + w10 * pc[o10] + w11 * pc[o11];
                xd[g * CG + c][pix] = __float2half(v);
            }
        }
    }
    __syncthreads();

    // ---- phase C: sk/km dots (wave-split), gate + softmax -> sknb ----
    {
        const int p   = t & 127;
        const int ctr = ((p >> 4) + 1) * HX + (p & 15) + 1;
        float acc[9];
#pragma unroll
        for (int k = 0; k < 9; ++k) acc[k] = 0.f;

        if (t < 128) {
            for (int c = 0; c < Cc; ++c) {
                const float xv = __half2float(xd[c][ctr]);
#pragma unroll
                for (int k = 0; k < 9; ++k)
                    acc[k] = fmaf(w_sk[k * Cc + c], xv, acc[k]);  // s_load
            }
        } else {
            for (int c = 0; c < Cc; ++c) {
                const float xv = __half2float(xd[c][ctr]);
#pragma unroll
                for (int k = 0; k < 9; ++k)
                    acc[k] = fmaf(w_km[k * Cc + c], xv, acc[k]);
            }
#pragma unroll
            for (int k = 0; k < 9; ++k) kmb[p * 9 + k] = acc[k];
        }
        __syncthreads();

        if (t < 128) {
            float sv[9], mx = -1e30f;
#pragma unroll
            for (int k = 0; k < 9; ++k) {
                const float z = kmb[p * 9 + k] + b_km[k];
                sv[k] = (acc[k] + b_sk[k]) / (1.f + __expf(-z));
                mx = fmaxf(mx, sv[k]);
            }
            float sum = 0.f;
#pragma unroll
            for (int k = 0; k < 9; ++k) { sv[k] = __expf(sv[k] - mx); sum += sv[k]; }
            const float inv = 1.f / sum;
#pragma unroll
            for (int k = 0; k < 9; ++k) sknb[p * 9 + k] = sv[k] * inv;
        }
    }
    __syncthreads();

    // ---- phase D: 3x3 dynamic conv, 2x2 pixel register blocking ----
    {
        const int sq    = t & 31;         // 8x4 squares of 2x2 pixels
        const int chunk = t >> 5;         // 8 channel chunks
        const int sqx = sq & 7, sqy = sq >> 3;
        const int hx0 = 2 * sqx, hy0 = 2 * sqy;
        const int p00 = (2 * sqy) * TW + 2 * sqx;

        float s00[9], s01[9], s10[9], s11[9];
#pragma unroll
        for (int k = 0; k < 9; ++k) {
            s00[k] = sknb[p00 * 9 + k];        s01[k] = sknb[(p00 + 1) * 9 + k];
            s10[k] = sknb[(p00 + TW) * 9 + k]; s11[k] = sknb[(p00 + TW + 1) * 9 + k];
        }
        const int orow0 = oy + 2 * sqy, ocol0 = ox + 2 * sqx;

#pragma unroll 2
        for (int i = 0; i < 8; ++i) {
            const int c = chunk * 8 + i;
            const __half* xc = &xd[c][0];
            float wd[4][4];
#pragma unroll
            for (int ry = 0; ry < 4; ++ry) {
                const int base = (hy0 + ry) * HX + hx0;
                const __half2 u0 = *reinterpret_cast<const __half2*>(&xc[base]);
                const __half2 u1 = *reinterpret_cast<const __half2*>(&xc[base + 2]);
                const float2 f0 = __half22float2(u0);
                const float2 f1 = __half22float2(u1);
                wd[ry][0] = f0.x; wd[ry][1] = f0.y; wd[ry][2] = f1.x; wd[ry][3] = f1.y;
            }
            float a00 = 0.f, a01 = 0.f, a10 = 0.f, a11 = 0.f;
#pragma unroll
            for (int ky = 0; ky < 3; ++ky)
#pragma unroll
                for (int kx = 0; kx < 3; ++kx) {
                    const int k = ky * 3 + kx;
                    a00 = fmaf(s00[k], wd[ky    ][kx    ], a00);
                    a01 = fmaf(s01[k], wd[ky    ][kx + 1], a01);
                    a10 = fmaf(s10[k], wd[ky + 1][kx    ], a10);
                    a11 = fmaf(s11[k], wd[ky + 1][kx + 1], a11);
                }
            float* ob = out + ((size_t)(b * Cc + c)) * (HOc * WOc)
                            + (size_t)orow0 * WOc + ocol0;
            *reinterpret_cast<float2*>(ob)       = make_float2(a00, a01);
            *reinterpret_cast<float2*>(ob + WOc) = make_float2(a10, a11);
        }
    }
}

// ---------------------------------------------------------------------------
extern "C" void kernel_launch(void* const* d_in, const int* in_sizes, int n_in,
                              void* d_out, int out_size, void* d_ws, size_t ws_size,
                              hipStream_t stream)
{
    const float* x      = (const float*)d_in[0];
    const float* w_off  = (const float*)d_in[1];
    const float* b_off  = (const float*)d_in[2];
    const float* w_offm = (const float*)d_in[3];
    const float* b_offm = (const float*)d_in[4];
    const float* w_sk   = (const float*)d_in[5];
    const float* b_sk   = (const float*)d_in[6];
    const float* w_km   = (const float*)d_in[7];
    const float* b_km   = (const float*)d_in[8];
    float* outp = (float*)d_out;

    const size_t off_bytes = (size_t)Bc * Gc * 8 * HW * sizeof(float); // 8 MiB
    if (ws_size < off_bytes) return;
    float* offbuf = (float*)d_ws;

    dim3 blk(256);
    dim3 g0(HW / (2 * 256), Bc * Gc);     // (32, 16): 2 pixels per thread
    hipLaunchKernelGGL(k0_offsets, g0, blk, 0, stream,
                       x, w_off, b_off, w_offm, b_offm, offbuf);

    dim3 g1(512, Bc);                     // 16x8 output tiles x b
    hipLaunchKernelGGL(k1_fused, g1, blk, 0, stream,
                       x, offbuf, w_sk, b_sk, w_km, b_km, outp);
}